// Round 1
// baseline (685.266 us; speedup 1.0000x reference)
//
#include <hip/hip_runtime.h>

// ---------------- problem constants (fixed by setup_inputs) ----------------
#define NB   32
#define NLQ  300
#define ND   256
#define NH   8
#define NHD  32
#define NLV  8400          // 80*80 + 40*40 + 20*20
#define MVAL (NB * NLV)    // 268800 rows of value
#define MQ   (NB * NLQ)    // 9600 query rows

typedef unsigned short u16b;
typedef __bf16 bf16x8 __attribute__((ext_vector_type(8)));
typedef float  f32x4v __attribute__((ext_vector_type(4)));

__device__ __forceinline__ u16b f2b(float f) {          // fp32 -> bf16 RNE
  union { float f; unsigned u; } x; x.f = f;
  unsigned r = x.u + 0x7fffu + ((x.u >> 16) & 1u);
  return (u16b)(r >> 16);
}
__device__ __forceinline__ float b2f(u16b h) {
  union { float f; unsigned u; } x; x.u = ((unsigned)h) << 16;
  return x.f;
}
__device__ __forceinline__ unsigned pack2(float a, float b) {
  return (unsigned)f2b(a) | ((unsigned)f2b(b) << 16);
}

// ---------------------------------------------------------------------------
// prep: transpose weights to [n][k] bf16. Wcat = [Woff | Wattn] with hi/lo
// split (query-side GEMM needs fp32-grade accuracy for sampling locations).
// grid 544 x 256
__global__ void prep_weights(const float* __restrict__ Wv, const float* __restrict__ Woff,
                             const float* __restrict__ Wattn, const float* __restrict__ Wout,
                             u16b* __restrict__ WvT, u16b* __restrict__ WcatH,
                             u16b* __restrict__ WcatL, u16b* __restrict__ WoutT) {
  const int n = blockIdx.x, k = threadIdx.x;
  if (n < 256) {
    WvT [n * 256 + k] = f2b(Wv  [k * 256 + n]);
    WoutT[n * 256 + k] = f2b(Wout[k * 256 + n]);
  } else {
    const int c = n - 256; // 0..287
    const float f = (c < 192) ? Woff[k * 192 + c] : Wattn[k * 96 + (c - 192)];
    const u16b hi = f2b(f);
    WcatH[c * 256 + k] = hi;
    WcatL[c * 256 + k] = f2b(f - b2f(hi));
  }
}

// ---------------------------------------------------------------------------
// MFMA GEMM, C[m][n] = sum_k A[m][k]*B[k][n], K=256, BK=32 (one 16x16x32 step).
// MODE 0: A=value fp32->bf16, B=WvT;   epilogue: bf16 v in [B][H][LV][32] (+bv)
// MODE 1: A=query split hi/lo, B=Wcat hi/lo (3-term split); epilogue: raw fp32+bias
// MODE 2: A=out_attn fp32->bf16, B=WoutT; epilogue: fp32 + bout -> d_out
template <int MODE>
__global__ __launch_bounds__(256, 2) void gemm_k(
    const float* __restrict__ A, const u16b* __restrict__ Bhi, const u16b* __restrict__ Blo,
    const float* __restrict__ bias0, const float* __restrict__ bias1,
    float* __restrict__ outf, u16b* __restrict__ outb) {
  constexpr int BM = (MODE == 1) ? 64 : 128;
  constexpr int BN = (MODE == 1) ? 288 : 256;
  constexpr int MT = BM / 32;   // m-tiles per wave (waves 2x2)
  constexpr int NT = BN / 32;   // n-tiles per wave
  constexpr int STR = 40;       // LDS row stride in bf16 (80B -> 2-way bank alias, free)

  __shared__ u16b Ah[BM * STR];
  __shared__ u16b Al[(MODE == 1) ? BM * STR : 2];
  __shared__ u16b Bh[BN * STR];
  __shared__ u16b Bl[(MODE == 1) ? BN * STR : 2];

  const int t = threadIdx.x;
  const int wid = t >> 6, lane = t & 63;
  const int lr = lane & 15, kq = lane >> 4;
  const int wm = wid >> 1, wn = wid & 1;
  const int row0 = blockIdx.x * BM;

  f32x4v acc[MT][NT];
  const f32x4v zero = {0.f, 0.f, 0.f, 0.f};
#pragma unroll
  for (int i = 0; i < MT; ++i)
#pragma unroll
    for (int j = 0; j < NT; ++j) acc[i][j] = zero;

  for (int ks = 0; ks < 8; ++ks) {
    const int k0 = ks * 32;
    // ---- stage A (fp32 -> bf16 [hi/lo]) ----
    constexpr int APASS = (BM * 32) / (256 * 8);
#pragma unroll
    for (int p = 0; p < APASS; ++p) {
      const int fi = (p * 256 + t) * 8;
      const int r = fi >> 5, kk = fi & 31;
      const float* src = A + (size_t)(row0 + r) * ND + k0 + kk;
      const float4 u0 = *(const float4*)src;
      const float4 u1 = *(const float4*)(src + 4);
      const float vv[8] = {u0.x, u0.y, u0.z, u0.w, u1.x, u1.y, u1.z, u1.w};
      uint4 hw;
      hw.x = pack2(vv[0], vv[1]); hw.y = pack2(vv[2], vv[3]);
      hw.z = pack2(vv[4], vv[5]); hw.w = pack2(vv[6], vv[7]);
      *(uint4*)&Ah[r * STR + kk] = hw;
      if constexpr (MODE == 1) {
        float lo[8];
#pragma unroll
        for (int j = 0; j < 8; ++j) lo[j] = vv[j] - b2f(f2b(vv[j]));
        uint4 lw;
        lw.x = pack2(lo[0], lo[1]); lw.y = pack2(lo[2], lo[3]);
        lw.z = pack2(lo[4], lo[5]); lw.w = pack2(lo[6], lo[7]);
        *(uint4*)&Al[r * STR + kk] = lw;
      }
    }
    // ---- stage B (already bf16 [n][k]) ----
    constexpr int BPASS = (BN * 32 + 2047) / 2048;
#pragma unroll
    for (int p = 0; p < BPASS; ++p) {
      const int fi = (p * 256 + t) * 8;
      if (fi < BN * 32) {
        const int n = fi >> 5, kk = fi & 31;
        *(uint4*)&Bh[n * STR + kk] = *(const uint4*)&Bhi[n * ND + k0 + kk];
        if constexpr (MODE == 1)
          *(uint4*)&Bl[n * STR + kk] = *(const uint4*)&Blo[n * ND + k0 + kk];
      }
    }
    __syncthreads();
    // ---- fragments + MFMA ----
    bf16x8 af[MT], alf[(MODE == 1) ? MT : 1];
#pragma unroll
    for (int im = 0; im < MT; ++im) {
      const int rr = wm * (BM / 2) + im * 16 + lr;
      af[im] = *(const bf16x8*)&Ah[rr * STR + kq * 8];
      if constexpr (MODE == 1) alf[im] = *(const bf16x8*)&Al[rr * STR + kq * 8];
    }
#pragma unroll
    for (int in = 0; in < NT; ++in) {
      const int nn = wn * (BN / 2) + in * 16 + lr;
      const bf16x8 bh = *(const bf16x8*)&Bh[nn * STR + kq * 8];
#pragma unroll
      for (int im = 0; im < MT; ++im)
        acc[im][in] = __builtin_amdgcn_mfma_f32_16x16x32_bf16(af[im], bh, acc[im][in], 0, 0, 0);
      if constexpr (MODE == 1) {
        const bf16x8 bl = *(const bf16x8*)&Bl[nn * STR + kq * 8];
#pragma unroll
        for (int im = 0; im < MT; ++im) {
          acc[im][in] = __builtin_amdgcn_mfma_f32_16x16x32_bf16(alf[im], bh, acc[im][in], 0, 0, 0);
          acc[im][in] = __builtin_amdgcn_mfma_f32_16x16x32_bf16(af[im], bl, acc[im][in], 0, 0, 0);
        }
      }
    }
    __syncthreads();
  }
  // ---- epilogue (C/D layout: col = lane&15, row = (lane>>4)*4 + reg) ----
#pragma unroll
  for (int im = 0; im < MT; ++im) {
    const int grb = row0 + wm * (BM / 2) + im * 16 + kq * 4;
#pragma unroll
    for (int in = 0; in < NT; ++in) {
      const int d = wn * (BN / 2) + in * 16 + lr;
#pragma unroll
      for (int rg = 0; rg < 4; ++rg) {
        const int gr = grb + rg;
        const float val = acc[im][in][rg];
        if constexpr (MODE == 0) {
          const int b = gr / NLV, pos = gr % NLV;
          const int h = d >> 5, ch = d & 31;
          outb[(((size_t)(b * NH + h)) * NLV + pos) * NHD + ch] = f2b(val + bias0[d]);
        } else if constexpr (MODE == 1) {
          const float bias = (d < 192) ? bias0[d] : bias1[d - 192];
          outf[(size_t)gr * 288 + d] = val + bias;
        } else {
          outf[(size_t)gr * ND + d] = val + bias0[d];
        }
      }
    }
  }
}

// ---------------------------------------------------------------------------
// per-(query,head): softmax over the 12 attn logits + sampling-loc transform
// grid 300 x 256
__global__ void loc_softmax(const float* __restrict__ rawq, const float* __restrict__ refp,
                            float* __restrict__ locb, float* __restrict__ attnb) {
  const int idx = blockIdx.x * 256 + threadIdx.x;
  if (idx >= MQ * NH) return;
  const int gq = idx >> 3, h = idx & 7;
  const float* r = rawq + (size_t)gq * 288;
  float lg[12], mx = -1e30f;
#pragma unroll
  for (int j = 0; j < 12; ++j) { lg[j] = r[192 + h * 12 + j]; mx = fmaxf(mx, lg[j]); }
  float s = 0.f;
#pragma unroll
  for (int j = 0; j < 12; ++j) { lg[j] = __expf(lg[j] - mx); s += lg[j]; }
  const float inv = 1.f / s;
#pragma unroll
  for (int j = 0; j < 12; ++j) attnb[(size_t)idx * 12 + j] = lg[j] * inv;
  const float* rp = refp + (size_t)gq * 12;
#pragma unroll
  for (int l = 0; l < 3; ++l) {
    const float cx = rp[l * 4 + 0], cy = rp[l * 4 + 1];
    const float wx = rp[l * 4 + 2] * 0.5f, wy = rp[l * 4 + 3] * 0.5f;
#pragma unroll
    for (int p = 0; p < 4; ++p) {
      const float ox = r[h * 24 + (l * 4 + p) * 2 + 0];
      const float oy = r[h * 24 + (l * 4 + p) * 2 + 1];
      locb[((size_t)idx * 12 + l * 4 + p) * 2 + 0] = cx + ox * wx;
      locb[((size_t)idx * 12 + l * 4 + p) * 2 + 1] = cy + oy * wy;
    }
  }
}

// ---------------------------------------------------------------------------
// bilinear sample + attention-weighted sum. block = one query (8 heads x 32 ch),
// grid 9600 x 256. v layout [B][H][LV][32]: a corner = 64B coalesced per h-group.
__global__ __launch_bounds__(256) void msda_sample(
    const u16b* __restrict__ Vws, const float* __restrict__ locb,
    const float* __restrict__ attnb, float* __restrict__ oattn) {
  const int gq = blockIdx.x;
  const int b = gq / NLQ;
  const int t = threadIdx.x;
  const int h = t >> 5, ch = t & 31;
  __shared__ float sloc[NH * 12 * 2];
  __shared__ float satt[NH * 12];
  if (t < 192) sloc[t] = locb[(size_t)gq * 192 + t];
  if (t < 96)  satt[t] = attnb[(size_t)gq * 96 + t];
  __syncthreads();
  const u16b* vb = Vws + ((size_t)(b * NH + h) * NLV) * NHD + ch;
  const int WLS[3] = {80, 40, 20};
  const int S0S[3] = {0, 6400, 8000};
  float acc = 0.f;
#pragma unroll
  for (int l = 0; l < 3; ++l) {
    const int Wl = WLS[l], Hl = WLS[l], s0 = S0S[l];
#pragma unroll
    for (int p = 0; p < 4; ++p) {
      const int si = h * 12 + l * 4 + p;
      const float w = satt[si];
      const float x = sloc[si * 2 + 0] * Wl - 0.5f;
      const float y = sloc[si * 2 + 1] * Hl - 0.5f;
      const float x0f = floorf(x), y0f = floorf(y);
      const float wx1 = x - x0f, wx0 = 1.f - wx1;
      const float wy1 = y - y0f, wy0 = 1.f - wy1;
      const int x0 = (int)x0f, y0i = (int)y0f;
      float c00 = 0.f, c10 = 0.f, c01 = 0.f, c11 = 0.f;
      if (y0i >= 0 && y0i < Hl) {
        const size_t rowb = (size_t)(s0 + y0i * Wl) * NHD;
        if (x0 >= 0 && x0 < Wl)         c00 = b2f(vb[rowb + (size_t)x0 * NHD]);
        if (x0 + 1 >= 0 && x0 + 1 < Wl) c10 = b2f(vb[rowb + (size_t)(x0 + 1) * NHD]);
      }
      const int y1i = y0i + 1;
      if (y1i >= 0 && y1i < Hl) {
        const size_t rowb = (size_t)(s0 + y1i * Wl) * NHD;
        if (x0 >= 0 && x0 < Wl)         c01 = b2f(vb[rowb + (size_t)x0 * NHD]);
        if (x0 + 1 >= 0 && x0 + 1 < Wl) c11 = b2f(vb[rowb + (size_t)(x0 + 1) * NHD]);
      }
      acc += w * (wy0 * (wx0 * c00 + wx1 * c10) + wy1 * (wx0 * c01 + wx1 * c11));
    }
  }
  oattn[(size_t)gq * ND + t] = acc;
}

// ---------------------------------------------------------------------------
extern "C" void kernel_launch(void* const* d_in, const int* in_sizes, int n_in,
                              void* d_out, int out_size, void* d_ws, size_t ws_size,
                              hipStream_t stream) {
  (void)in_sizes; (void)n_in; (void)out_size; (void)ws_size;
  const float* query = (const float*)d_in[0];
  const float* refp  = (const float*)d_in[1];
  const float* value = (const float*)d_in[2];
  const float* Wv    = (const float*)d_in[5];
  const float* bv    = (const float*)d_in[6];
  const float* Woff  = (const float*)d_in[7];
  const float* boff  = (const float*)d_in[8];
  const float* Wattn = (const float*)d_in[9];
  const float* battn = (const float*)d_in[10];
  const float* Wout  = (const float*)d_in[11];
  const float* bout  = (const float*)d_in[12];
  float* out = (float*)d_out;

  // workspace carve-up (~162.3 MiB total)
  char* w = (char*)d_ws;
  u16b*  v_ws  = (u16b*)w;  w += (size_t)MVAL * ND * 2;       // 137,625,600
  u16b*  WvT   = (u16b*)w;  w += (size_t)256 * 256 * 2;
  u16b*  WoutT = (u16b*)w;  w += (size_t)256 * 256 * 2;
  u16b*  WcatH = (u16b*)w;  w += (size_t)288 * 256 * 2;
  u16b*  WcatL = (u16b*)w;  w += (size_t)288 * 256 * 2;
  float* rawq  = (float*)w; w += (size_t)MQ * 288 * 4;
  float* locb  = (float*)w; w += (size_t)MQ * NH * 12 * 2 * 4;
  float* attnb = (float*)w; w += (size_t)MQ * NH * 12 * 4;
  float* oattn = (float*)w; w += (size_t)MQ * ND * 4;

  prep_weights<<<544, 256, 0, stream>>>(Wv, Woff, Wattn, Wout, WvT, WcatH, WcatL, WoutT);
  gemm_k<0><<<MVAL / 128, 256, 0, stream>>>(value, WvT, nullptr, bv, nullptr, nullptr, v_ws);
  gemm_k<1><<<MQ / 64, 256, 0, stream>>>(query, WcatH, WcatL, boff, battn, rawq, nullptr);
  loc_softmax<<<(MQ * NH + 255) / 256, 256, 0, stream>>>(rawq, refp, locb, attnb);
  msda_sample<<<MQ, 256, 0, stream>>>(v_ws, locb, attnb, oattn);
  gemm_k<2><<<MQ / 128, 256, 0, stream>>>(oattn, WoutT, nullptr, bout, nullptr, out, nullptr);
}

// Round 2
// 543.612 us; speedup vs baseline: 1.2606x; 1.2606x over previous
//
#include <hip/hip_runtime.h>

// ---------------- problem constants (fixed by setup_inputs) ----------------
#define NB   32
#define NLQ  300
#define ND   256
#define NH   8
#define NHD  32
#define NLV  8400          // 80*80 + 40*40 + 20*20
#define MVAL (NB * NLV)    // 268800 rows of value
#define MQ   (NB * NLQ)    // 9600 query rows

typedef unsigned short u16b;
typedef __bf16 bf16x8 __attribute__((ext_vector_type(8)));
typedef float  f32x4v __attribute__((ext_vector_type(4)));

__device__ __forceinline__ u16b f2b(float f) {          // fp32 -> bf16 RNE
  union { float f; unsigned u; } x; x.f = f;
  unsigned r = x.u + 0x7fffu + ((x.u >> 16) & 1u);
  return (u16b)(r >> 16);
}
__device__ __forceinline__ float b2f(u16b h) {
  union { float f; unsigned u; } x; x.u = ((unsigned)h) << 16;
  return x.f;
}
__device__ __forceinline__ unsigned pack2(float a, float b) {
  return (unsigned)f2b(a) | ((unsigned)f2b(b) << 16);
}
__device__ __forceinline__ float blo(unsigned u) {      // bf16 in low half -> f32
  union { float f; unsigned v; } x; x.v = u << 16; return x.f;
}
__device__ __forceinline__ float bhi(unsigned u) {      // bf16 in high half -> f32
  union { float f; unsigned v; } x; x.v = u & 0xffff0000u; return x.f;
}

// ---------------------------------------------------------------------------
// prep: transpose weights to [n][k] bf16. Wcat = [Woff | Wattn] with hi/lo
// split (query-side GEMM needs fp32-grade accuracy for sampling locations).
// grid 544 x 256
__global__ void prep_weights(const float* __restrict__ Wv, const float* __restrict__ Woff,
                             const float* __restrict__ Wattn, const float* __restrict__ Wout,
                             u16b* __restrict__ WvT, u16b* __restrict__ WcatH,
                             u16b* __restrict__ WcatL, u16b* __restrict__ WoutT) {
  const int n = blockIdx.x, k = threadIdx.x;
  if (n < 256) {
    WvT [n * 256 + k] = f2b(Wv  [k * 256 + n]);
    WoutT[n * 256 + k] = f2b(Wout[k * 256 + n]);
  } else {
    const int c = n - 256; // 0..287
    const float f = (c < 192) ? Woff[k * 192 + c] : Wattn[k * 96 + (c - 192)];
    const u16b hi = f2b(f);
    WcatH[c * 256 + k] = hi;
    WcatL[c * 256 + k] = f2b(f - b2f(hi));
  }
}

// ---------------------------------------------------------------------------
// MFMA GEMM, C[m][n] = sum_k A[m][k]*B[k][n], K=256, BK=32, BN=256.
// MODE 0: BM=128. A=value fp32->bf16, B=WvT; epilogue bf16 v [B][H][LV][32] (+bv)
// MODE 2: BM=32.  A=oattn fp32->bf16, B=WoutT; epilogue fp32 + bout -> d_out
template <int MODE>
__global__ __launch_bounds__(256, 2) void gemm_k(
    const float* __restrict__ A, const u16b* __restrict__ Bhi,
    const float* __restrict__ bias0, float* __restrict__ outf, u16b* __restrict__ outb) {
  constexpr int BM = (MODE == 0) ? 128 : 32;
  constexpr int BN = 256;
  constexpr int MT = BM / 32;
  constexpr int NT = BN / 32;
  constexpr int STR = 40;       // LDS row stride in bf16 (80B -> 2-way alias, free)

  __shared__ u16b Ah[BM * STR];
  __shared__ u16b Bh[BN * STR];

  const int t = threadIdx.x;
  const int wid = t >> 6, lane = t & 63;
  const int lr = lane & 15, kq = lane >> 4;
  const int wm = wid >> 1, wn = wid & 1;
  const int row0 = blockIdx.x * BM;

  f32x4v acc[MT][NT];
  const f32x4v zero = {0.f, 0.f, 0.f, 0.f};
#pragma unroll
  for (int i = 0; i < MT; ++i)
#pragma unroll
    for (int j = 0; j < NT; ++j) acc[i][j] = zero;

  for (int ks = 0; ks < 8; ++ks) {
    const int k0 = ks * 32;
    // ---- stage A (fp32 -> bf16) ----
#pragma unroll
    for (int fi = t * 8; fi < BM * 32; fi += 2048) {
      const int r = fi >> 5, kk = fi & 31;
      const float* src = A + (size_t)(row0 + r) * ND + k0 + kk;
      const float4 u0 = *(const float4*)src;
      const float4 u1 = *(const float4*)(src + 4);
      uint4 hw;
      hw.x = pack2(u0.x, u0.y); hw.y = pack2(u0.z, u0.w);
      hw.z = pack2(u1.x, u1.y); hw.w = pack2(u1.z, u1.w);
      *(uint4*)&Ah[r * STR + kk] = hw;
    }
    // ---- stage B (already bf16 [n][k]) ----
#pragma unroll
    for (int fi = t * 8; fi < BN * 32; fi += 2048) {
      const int n = fi >> 5, kk = fi & 31;
      *(uint4*)&Bh[n * STR + kk] = *(const uint4*)&Bhi[n * ND + k0 + kk];
    }
    __syncthreads();
    bf16x8 af[MT];
#pragma unroll
    for (int im = 0; im < MT; ++im) {
      const int rr = wm * (BM / 2) + im * 16 + lr;
      af[im] = *(const bf16x8*)&Ah[rr * STR + kq * 8];
    }
#pragma unroll
    for (int in = 0; in < NT; ++in) {
      const int nn = wn * (BN / 2) + in * 16 + lr;
      const bf16x8 bh = *(const bf16x8*)&Bh[nn * STR + kq * 8];
#pragma unroll
      for (int im = 0; im < MT; ++im)
        acc[im][in] = __builtin_amdgcn_mfma_f32_16x16x32_bf16(af[im], bh, acc[im][in], 0, 0, 0);
    }
    __syncthreads();
  }
  // ---- epilogue (C/D layout: col = lane&15, row = (lane>>4)*4 + reg) ----
#pragma unroll
  for (int im = 0; im < MT; ++im) {
    const int grb = row0 + wm * (BM / 2) + im * 16 + kq * 4;
#pragma unroll
    for (int in = 0; in < NT; ++in) {
      const int d = wn * (BN / 2) + in * 16 + lr;
#pragma unroll
      for (int rg = 0; rg < 4; ++rg) {
        const int gr = grb + rg;
        const float val = acc[im][in][rg] + bias0[d];
        if constexpr (MODE == 0) {
          const int b = gr / NLV, pos = gr % NLV;
          const int h = d >> 5, ch = d & 31;
          outb[(((size_t)(b * NH + h)) * NLV + pos) * NHD + ch] = f2b(val);
        } else {
          outf[(size_t)gr * ND + d] = val;
        }
      }
    }
  }
}

// ---------------------------------------------------------------------------
// query-head GEMM (BM=32, BN=288, K=256) with hi/lo bf16 split for fp32-grade
// accuracy, FUSED with softmax + sampling-loc epilogue.
// pb[gq][288]: [0..192) = loc (x,y) pairs indexed (h*12 + l*4 + p), [192..288) = attn.
// grid 300 x 256
__global__ __launch_bounds__(256, 2) void gemm_qh(
    const float* __restrict__ A, const u16b* __restrict__ Bhi, const u16b* __restrict__ Blo,
    const float* __restrict__ boff, const float* __restrict__ battn,
    const float* __restrict__ refp, float* __restrict__ pb) {
  constexpr int BM = 32, BN = 288, NT = 9, STR = 40, RSTR = 289;
  __shared__ __align__(16) char smem[51200];
  u16b* Ah = (u16b*)smem;                    // 32*40*2   = 2560
  u16b* Al = (u16b*)(smem + 2560);           // 2560
  u16b* Bh = (u16b*)(smem + 5120);           // 288*40*2  = 23040
  u16b* Bl = (u16b*)(smem + 28160);          // 23040
  float* raw = (float*)(smem + 5120);        // overlay: 32*289*4 = 36992 (after K-loop)

  const int t = threadIdx.x;
  const int wid = t >> 6, lane = t & 63;
  const int lr = lane & 15, kq = lane >> 4;
  const int wm = wid >> 1, wn = wid & 1;
  const int row0 = blockIdx.x * BM;

  f32x4v acc[NT];
  const f32x4v zero = {0.f, 0.f, 0.f, 0.f};
#pragma unroll
  for (int j = 0; j < NT; ++j) acc[j] = zero;

  for (int ks = 0; ks < 8; ++ks) {
    const int k0 = ks * 32;
    if (t < 128) {   // A: 32x32 fp32 -> hi/lo bf16
      const int fi = t * 8;
      const int r = fi >> 5, kk = fi & 31;
      const float* src = A + (size_t)(row0 + r) * ND + k0 + kk;
      const float4 u0 = *(const float4*)src;
      const float4 u1 = *(const float4*)(src + 4);
      const float vv[8] = {u0.x, u0.y, u0.z, u0.w, u1.x, u1.y, u1.z, u1.w};
      uint4 hw;
      hw.x = pack2(vv[0], vv[1]); hw.y = pack2(vv[2], vv[3]);
      hw.z = pack2(vv[4], vv[5]); hw.w = pack2(vv[6], vv[7]);
      *(uint4*)&Ah[r * STR + kk] = hw;
      float lo[8];
#pragma unroll
      for (int j = 0; j < 8; ++j) lo[j] = vv[j] - b2f(f2b(vv[j]));
      uint4 lw;
      lw.x = pack2(lo[0], lo[1]); lw.y = pack2(lo[2], lo[3]);
      lw.z = pack2(lo[4], lo[5]); lw.w = pack2(lo[6], lo[7]);
      *(uint4*)&Al[r * STR + kk] = lw;
    }
#pragma unroll
    for (int fi = t * 8; fi < BN * 32; fi += 2048) {
      const int n = fi >> 5, kk = fi & 31;
      *(uint4*)&Bh[n * STR + kk] = *(const uint4*)&Bhi[n * ND + k0 + kk];
      *(uint4*)&Bl[n * STR + kk] = *(const uint4*)&Blo[n * ND + k0 + kk];
    }
    __syncthreads();
    const int rr = wm * 16 + lr;
    const bf16x8 af  = *(const bf16x8*)&Ah[rr * STR + kq * 8];
    const bf16x8 alf = *(const bf16x8*)&Al[rr * STR + kq * 8];
#pragma unroll
    for (int in = 0; in < NT; ++in) {
      const int nn = wn * 144 + in * 16 + lr;
      const bf16x8 bh = *(const bf16x8*)&Bh[nn * STR + kq * 8];
      const bf16x8 bl = *(const bf16x8*)&Bl[nn * STR + kq * 8];
      acc[in] = __builtin_amdgcn_mfma_f32_16x16x32_bf16(af,  bh, acc[in], 0, 0, 0);
      acc[in] = __builtin_amdgcn_mfma_f32_16x16x32_bf16(alf, bh, acc[in], 0, 0, 0);
      acc[in] = __builtin_amdgcn_mfma_f32_16x16x32_bf16(af,  bl, acc[in], 0, 0, 0);
    }
    __syncthreads();
  }
  // raw[q][288] into LDS (overlays B staging; safe after trailing barrier)
#pragma unroll
  for (int in = 0; in < NT; ++in) {
    const int d = wn * 144 + in * 16 + lr;
    const float bias = (d < 192) ? boff[d] : battn[d - 192];
#pragma unroll
    for (int rg = 0; rg < 4; ++rg) {
      const int row = wm * 16 + kq * 4 + rg;
      raw[row * RSTR + d] = acc[in][rg] + bias;
    }
  }
  __syncthreads();
  // fused softmax + loc transform: thread t -> (q = t>>3, h = t&7)
  {
    const int q = t >> 3, h = t & 7;
    const int gq = row0 + q;
    const float* r = raw + q * RSTR;
    float lg[12], mx = -1e30f;
#pragma unroll
    for (int j = 0; j < 12; ++j) { lg[j] = r[192 + h * 12 + j]; mx = fmaxf(mx, lg[j]); }
    float s = 0.f;
#pragma unroll
    for (int j = 0; j < 12; ++j) { lg[j] = __expf(lg[j] - mx); s += lg[j]; }
    const float inv = 1.f / s;
    float* po = pb + (size_t)gq * 288;
#pragma unroll
    for (int j = 0; j < 12; ++j) po[192 + h * 12 + j] = lg[j] * inv;
    const float* rp = refp + (size_t)gq * 12;
#pragma unroll
    for (int l = 0; l < 3; ++l) {
      const float cx = rp[l * 4 + 0], cy = rp[l * 4 + 1];
      const float wx = rp[l * 4 + 2] * 0.5f, wy = rp[l * 4 + 3] * 0.5f;
#pragma unroll
      for (int p = 0; p < 4; ++p) {
        const float ox = r[h * 24 + (l * 4 + p) * 2 + 0];
        const float oy = r[h * 24 + (l * 4 + p) * 2 + 1];
        po[(h * 12 + l * 4 + p) * 2 + 0] = cx + ox * wx;
        po[(h * 12 + l * 4 + p) * 2 + 1] = cy + oy * wy;
      }
    }
  }
}

// ---------------------------------------------------------------------------
// bilinear sample + attention-weighted sum, v2: one WAVE per query,
// lane = h*8 + c4 (4 channels each, uint2 = 8B loads), branch-free clamped
// loads with validity folded into weights. grid 2400 x 256 (4 queries/block).
__global__ __launch_bounds__(256) void msda_sample(
    const u16b* __restrict__ Vws, const float* __restrict__ pb,
    float* __restrict__ oattn) {
  const int gq0 = blockIdx.x * 4;
  const int t = threadIdx.x;
  __shared__ float spb[4 * 288];
  for (int i = t; i < 4 * 288; i += 256) spb[i] = pb[(size_t)gq0 * 288 + i];
  __syncthreads();
  const int wave = t >> 6, lane = t & 63;
  const int h = lane >> 3, c4 = lane & 7;
  const int gq = gq0 + wave;
  const int b = gq / NLQ;
  const float* P = spb + wave * 288;
  const u16b* vb = Vws + ((size_t)(b * NH + h) * NLV) * NHD + c4 * 4;
  const int WLS[3] = {80, 40, 20};
  const int S0S[3] = {0, 6400, 8000};
  float4 acc = {0.f, 0.f, 0.f, 0.f};
#pragma unroll
  for (int l = 0; l < 3; ++l) {
    const int Wl = WLS[l], s0 = S0S[l];
    const float Wf = (float)Wl;
#pragma unroll
    for (int p = 0; p < 4; ++p) {
      const int si = h * 12 + l * 4 + p;
      const float aw = P[192 + si];
      const float fx = P[si * 2 + 0] * Wf - 0.5f;
      const float fy = P[si * 2 + 1] * Wf - 0.5f;
      const float x0f = floorf(fx), y0f = floorf(fy);
      const float wx1 = fx - x0f, wx0 = 1.f - wx1;
      const float wy1 = fy - y0f, wy0 = 1.f - wy1;
      const int ix = (int)x0f, iy = (int)y0f;
      const float ax0 = ((unsigned)ix < (unsigned)Wl) ? wx0 : 0.f;
      const float ax1 = ((unsigned)(ix + 1) < (unsigned)Wl) ? wx1 : 0.f;
      const float ay0 = ((unsigned)iy < (unsigned)Wl) ? aw * wy0 : 0.f;
      const float ay1 = ((unsigned)(iy + 1) < (unsigned)Wl) ? aw * wy1 : 0.f;
      const int cx0 = min(max(ix, 0), Wl - 1);
      const int cx1 = min(max(ix + 1, 0), Wl - 1);
      const int cy0 = min(max(iy, 0), Wl - 1);
      const int cy1 = min(max(iy + 1, 0), Wl - 1);
      const int r0 = s0 + cy0 * Wl, r1 = s0 + cy1 * Wl;
      const uint2 u00 = *(const uint2*)(vb + (size_t)(r0 + cx0) * NHD);
      const uint2 u10 = *(const uint2*)(vb + (size_t)(r0 + cx1) * NHD);
      const uint2 u01 = *(const uint2*)(vb + (size_t)(r1 + cx0) * NHD);
      const uint2 u11 = *(const uint2*)(vb + (size_t)(r1 + cx1) * NHD);
      const float w00 = ay0 * ax0, w10 = ay0 * ax1;
      const float w01 = ay1 * ax0, w11 = ay1 * ax1;
      acc.x = fmaf(w00, blo(u00.x), acc.x); acc.y = fmaf(w00, bhi(u00.x), acc.y);
      acc.z = fmaf(w00, blo(u00.y), acc.z); acc.w = fmaf(w00, bhi(u00.y), acc.w);
      acc.x = fmaf(w10, blo(u10.x), acc.x); acc.y = fmaf(w10, bhi(u10.x), acc.y);
      acc.z = fmaf(w10, blo(u10.y), acc.z); acc.w = fmaf(w10, bhi(u10.y), acc.w);
      acc.x = fmaf(w01, blo(u01.x), acc.x); acc.y = fmaf(w01, bhi(u01.x), acc.y);
      acc.z = fmaf(w01, blo(u01.y), acc.z); acc.w = fmaf(w01, bhi(u01.y), acc.w);
      acc.x = fmaf(w11, blo(u11.x), acc.x); acc.y = fmaf(w11, bhi(u11.x), acc.y);
      acc.z = fmaf(w11, blo(u11.y), acc.z); acc.w = fmaf(w11, bhi(u11.y), acc.w);
    }
  }
  *(float4*)(oattn + (size_t)gq * ND + h * NHD + c4 * 4) = acc;
}

// ---------------------------------------------------------------------------
extern "C" void kernel_launch(void* const* d_in, const int* in_sizes, int n_in,
                              void* d_out, int out_size, void* d_ws, size_t ws_size,
                              hipStream_t stream) {
  (void)in_sizes; (void)n_in; (void)out_size; (void)ws_size;
  const float* query = (const float*)d_in[0];
  const float* refp  = (const float*)d_in[1];
  const float* value = (const float*)d_in[2];
  const float* Wv    = (const float*)d_in[5];
  const float* bv    = (const float*)d_in[6];
  const float* Woff  = (const float*)d_in[7];
  const float* boff  = (const float*)d_in[8];
  const float* Wattn = (const float*)d_in[9];
  const float* battn = (const float*)d_in[10];
  const float* Wout  = (const float*)d_in[11];
  const float* bout  = (const float*)d_in[12];
  float* out = (float*)d_out;

  // workspace carve-up (~159 MiB total)
  char* w = (char*)d_ws;
  u16b*  v_ws  = (u16b*)w;  w += (size_t)MVAL * ND * 2;       // 137,625,600
  u16b*  WvT   = (u16b*)w;  w += (size_t)256 * 256 * 2;
  u16b*  WoutT = (u16b*)w;  w += (size_t)256 * 256 * 2;
  u16b*  WcatH = (u16b*)w;  w += (size_t)288 * 256 * 2;
  u16b*  WcatL = (u16b*)w;  w += (size_t)288 * 256 * 2;
  float* pb    = (float*)w; w += (size_t)MQ * 288 * 4;        // loc+attn packed
  float* oattn = (float*)w; w += (size_t)MQ * ND * 4;

  prep_weights<<<544, 256, 0, stream>>>(Wv, Woff, Wattn, Wout, WvT, WcatH, WcatL, WoutT);
  gemm_k<0><<<MVAL / 128, 256, 0, stream>>>(value, WvT, bv, nullptr, v_ws);
  gemm_qh<<<MQ / 32, 256, 0, stream>>>(query, WcatH, WcatL, boff, battn, refp, pb);
  msda_sample<<<MQ / 4, 256, 0, stream>>>(v_ws, pb, oattn);
  gemm_k<2><<<MQ / 32, 256, 0, stream>>>(oattn, WoutT, bout, out, nullptr);
}